// Round 19
// baseline (63.713 us; speedup 1.0000x reference)
//
#include <hip/hip_runtime.h>
#include <hip/hip_bf16.h>
#include <math.h>

// Problem constants
#define B_    16
#define C_    256
#define L_    64
#define N_    8192
#define HEAD_ 8
#define HC_   32        // C/HEAD
#define M_    12

#define SQRT32F 5.656854249492380f
#define PI_F    3.14159265358979323846f
#define BN_INV  0.99999500003749969f     // 1/sqrt(1+1e-5)

typedef float v4f __attribute__((ext_vector_type(4)));

// ---------------------------------------------------------------------------
// Kernel 1: fused encoder+decoder per (b,h). 128 blocks x 1024 threads.
// Identical dataflow to R14 (52.4 us best) but 16 waves/block -> 4 waves/SIMD
// (R14 had 2): attacks the measured latency-bound regime (R17 counters:
// VALUBusy 8%, Occupancy 20%).
// ---------------------------------------------------------------------------
__global__ __launch_bounds__(1024) void fused_enc(
    const float* __restrict__ xt, const float* __restrict__ enc_w,
    const float* __restrict__ enc_b, const float* __restrict__ weights,
    const float* __restrict__ dec_w, const float* __restrict__ dec_b,
    const float* __restrict__ mt, float* __restrict__ xnp_out)
{
    __shared__ float Xs[C_][L_];          // 64 KB   xt[b] as [c][l]
    __shared__ float qkv_s[96][68];       // 26.1 KB rows 0..31 q, 32..63 k, 64..95 v
    __shared__ float P[L_][68];           // 17.4 KB
    __shared__ float enc_t[HC_][68];      // 8.7 KB
    __shared__ float wts[HC_][24];        // 3 KB
    __shared__ float qvs[HC_];
    __shared__ float aw[L_];
    const int t = threadIdx.x;            // 0..1023
    const int b = blockIdx.x >> 3;
    const int h = blockIdx.x & 7;
    const float* xtb = xt + (size_t)b * (C_ * L_);

    // ---- phase 1: stage xt[b] + weights slice ----
    #pragma unroll
    for (int i = 0; i < 4; ++i) {
        int q = t + i * 1024;             // 0..4095 quads
        int c = q >> 4, l4 = (q & 15) * 4;
        *reinterpret_cast<float4*>(&Xs[c][l4]) =
            *reinterpret_cast<const float4*>(&xtb[q * 4]);
    }
    if (t < HC_ * 24)
        wts[t / 24][t % 24] = weights[(h * HC_) * 24 + t];
    __syncthreads();

    // ---- phase 2: qkv GEMM, 3 rows x 2 cols per thread (1024 threads) ----
    {
        const int tx = t & 31;                 // cols tx*2, tx*2+1
        const int ty = t >> 5;                 // 0..31: rows ty*3..+2
        float acc[3][2] = {};
        int og[3];
        const float* wrow[3];
        #pragma unroll
        for (int r = 0; r < 3; ++r) {
            int o_loc = ty * 3 + r;            // 0..95
            int sec = o_loc >> 5, cc = o_loc & 31;
            og[r] = sec * C_ + h * HC_ + cc;
            wrow[r] = enc_w + (size_t)og[r] * C_;
        }
        #pragma unroll 2
        for (int c0 = 0; c0 < C_; c0 += 4) {
            float2 x0 = *reinterpret_cast<const float2*>(&Xs[c0 + 0][tx * 2]);
            float2 x1 = *reinterpret_cast<const float2*>(&Xs[c0 + 1][tx * 2]);
            float2 x2 = *reinterpret_cast<const float2*>(&Xs[c0 + 2][tx * 2]);
            float2 x3 = *reinterpret_cast<const float2*>(&Xs[c0 + 3][tx * 2]);
            #pragma unroll
            for (int r = 0; r < 3; ++r) {
                float4 w4 = *reinterpret_cast<const float4*>(&wrow[r][c0]);
                acc[r][0] += w4.x * x0.x + w4.y * x1.x + w4.z * x2.x + w4.w * x3.x;
                acc[r][1] += w4.x * x0.y + w4.y * x1.y + w4.z * x2.y + w4.w * x3.y;
            }
        }
        #pragma unroll
        for (int r = 0; r < 3; ++r) {
            float bias = enc_b[og[r]];
            *reinterpret_cast<float2*>(&qkv_s[ty * 3 + r][tx * 2]) =
                make_float2(acc[r][0] + bias, acc[r][1] + bias);
        }
    }
    // qv: 32 rows x 4 partial-threads, shfl-xor combine (R14 verbatim)
    if (t < 128) {
        int cc = t >> 2, part = t & 3;
        const float* wr = dec_w + (size_t)(h * HC_ + cc) * C_ + part * 64;
        const float* mp = mt + part * 64;
        float s = 0.f;
        #pragma unroll
        for (int j = 0; j < 16; ++j) {
            float4 w4 = *reinterpret_cast<const float4*>(&wr[j * 4]);
            float4 m4 = *reinterpret_cast<const float4*>(&mp[j * 4]);
            s += w4.x * m4.x + w4.y * m4.y + w4.z * m4.z + w4.w * m4.w;
        }
        s += __shfl_xor(s, 1);
        s += __shfl_xor(s, 2);
        if (part == 0) qvs[cc] = s + dec_b[h * HC_ + cc];
    }
    __syncthreads();

    // ---- phase 3a: scores, 1l x 4lp per thread (1024 threads) ----
    {
        const int l   = t >> 4;           // 0..63
        const int lp0 = (t & 15) * 4;
        float4 a4 = {0.f, 0.f, 0.f, 0.f};
        #pragma unroll
        for (int cc = 0; cc < HC_; ++cc) {
            float qv_ = qkv_s[cc][l];
            float4 k4 = *reinterpret_cast<const float4*>(&qkv_s[32 + cc][lp0]);
            a4.x += qv_ * k4.x; a4.y += qv_ * k4.y;
            a4.z += qv_ * k4.z; a4.w += qv_ * k4.w;
        }
        a4.x *= SQRT32F; a4.y *= SQRT32F; a4.z *= SQRT32F; a4.w *= SQRT32F;
        *reinterpret_cast<float4*>(&P[l][lp0]) = a4;
    }
    __syncthreads();

    // ---- phase 3b: softmax, 16 threads/row (R16-proven reduce) ----
    {
        int l = t >> 4, p0 = (t & 15) * 4;
        float m = -1e30f;
        #pragma unroll
        for (int j = 0; j < 4; ++j) m = fmaxf(m, P[l][p0 + j]);
        m = fmaxf(m, __shfl_xor(m, 1));
        m = fmaxf(m, __shfl_xor(m, 2));
        m = fmaxf(m, __shfl_xor(m, 4));
        m = fmaxf(m, __shfl_xor(m, 8));
        float sum = 0.f;
        #pragma unroll
        for (int j = 0; j < 4; ++j) {
            float e = __expf(P[l][p0 + j] - m);
            P[l][p0 + j] = e;
            sum += e;
        }
        sum += __shfl_xor(sum, 1);
        sum += __shfl_xor(sum, 2);
        sum += __shfl_xor(sum, 4);
        sum += __shfl_xor(sum, 8);
        float inv = 1.0f / sum;
        #pragma unroll
        for (int j = 0; j < 4; ++j) P[l][p0 + j] *= inv;
    }
    __syncthreads();

    // ---- phase 3c: PV (2l x 1cc) + Fourier recurrence + residual ----
    {
        const int l0 = (t & 31) * 2;      // 0..62
        const int cc = t >> 5;            // 0..31
        float a0 = 0.f, a1 = 0.f;
        #pragma unroll
        for (int sq = 0; sq < 16; ++sq) {
            float4 p0v = *reinterpret_cast<const float4*>(&P[l0 + 0][sq * 4]);
            float4 p1v = *reinterpret_cast<const float4*>(&P[l0 + 1][sq * 4]);
            float4 v4  = *reinterpret_cast<const float4*>(&qkv_s[64 + cc][sq * 4]);
            a0 += p0v.x * v4.x + p0v.y * v4.y + p0v.z * v4.z + p0v.w * v4.w;
            a1 += p1v.x * v4.x + p1v.y * v4.y + p1v.z * v4.z + p1v.w * v4.w;
        }
        const float* wrf = wts[cc];
        const int c = h * HC_ + cc;
        float av[2] = {a0, a1};
        float vv[2];
        #pragma unroll
        for (int i = 0; i < 2; ++i) {
            float val = Xs[c][l0 + i] + wrf[M_];   // m=0: sin=0, cos=1
            float base = av[i] * (PI_F / (float)M_);
            float s1, c1;
            __sincosf(base, &s1, &c1);
            float sm = 0.f, cm = 1.f;
            #pragma unroll
            for (int m = 1; m < M_; ++m) {
                float sp = sm * c1 + cm * s1;
                float cp = cm * c1 - sm * s1;
                sm = sp; cm = cp;
                val += wrf[m] * sm + wrf[M_ + m] * cm;
            }
            vv[i] = val;
        }
        *reinterpret_cast<float2*>(&enc_t[cc][l0]) = make_float2(vv[0], vv[1]);
    }
    __syncthreads();

    // ---- phase 4: decoder attention (constant query) ----
    if (t < L_) {
        float s = 0.f;
        #pragma unroll
        for (int cc = 0; cc < HC_; ++cc) s += qvs[cc] * enc_t[cc][t];
        s *= SQRT32F;
        float m = s;
        #pragma unroll
        for (int off = 32; off >= 1; off >>= 1) m = fmaxf(m, __shfl_xor(m, off));
        float e = __expf(s - m);
        float sum = e;
        #pragma unroll
        for (int off = 32; off >= 1; off >>= 1) sum += __shfl_xor(sum, off);
        aw[t] = e / sum;
    }
    __syncthreads();
    if (t < HC_) {
        float a = 0.f;
        #pragma unroll
        for (int k4 = 0; k4 < L_; k4 += 4) {
            float4 a4 = *reinterpret_cast<const float4*>(&aw[k4]);
            float4 v4 = *reinterpret_cast<const float4*>(&enc_t[t][k4]);
            a += a4.x * v4.x + a4.y * v4.y + a4.z * v4.z + a4.w * v4.w;
        }
        int c = h * HC_ + t;
        xnp_out[b * C_ + c] = a + mt[c];
    }
}

// ---------------------------------------------------------------------------
// Kernel 2: fc blocks first, nontemporal streaming stores. (proven R10)
// ---------------------------------------------------------------------------
__global__ __launch_bounds__(256) void bcast_fc(const float* __restrict__ xnp,
                                                const float* __restrict__ fc1_w,
                                                const float* __restrict__ fc1_g,
                                                const float* __restrict__ fc1_b,
                                                const float* __restrict__ fc2_w,
                                                const float* __restrict__ fc2_g,
                                                const float* __restrict__ fc2_b,
                                                float* __restrict__ out) {
    const int t = threadIdx.x;
    const int blk = blockIdx.x;
    if (blk >= 16) {
        int rowid = blk - 16;                 // (b,c) row
        float v = xnp[rowid];
        v4f V = {v, v, v, v};
        v4f* row = reinterpret_cast<v4f*>(out + (size_t)rowid * N_);
        #pragma unroll
        for (int i = 0; i < 8; ++i)
            __builtin_nontemporal_store(V, &row[t + i * 256]);   // 2048 x 16B
    } else {
        int b = blk;
        __shared__ float xs[C_];
        __shared__ float y1[C_];
        __shared__ float y2s[4];
        xs[t] = xnp[b * C_ + t];
        __syncthreads();
        // fc1 + BN + LeakyReLU
        {
            const float* wrow = fc1_w + (size_t)t * C_;
            float s = 0.f;
            #pragma unroll 8
            for (int c4 = 0; c4 < C_; c4 += 4) {
                float4 w4 = *reinterpret_cast<const float4*>(&wrow[c4]);
                float4 x4 = *reinterpret_cast<const float4*>(&xs[c4]);
                s += w4.x * x4.x + w4.y * x4.y + w4.z * x4.z + w4.w * x4.w;
            }
            float y = fc1_g[t] * s * BN_INV + fc1_b[t];
            y1[t] = (y >= 0.f) ? y : 0.2f * y;
        }
        __syncthreads();
        if (t < 3) {
            const float* wrow = fc2_w + t * C_;
            float s = 0.f;
            #pragma unroll 8
            for (int c4 = 0; c4 < C_; c4 += 4) {
                float4 w4 = *reinterpret_cast<const float4*>(&wrow[c4]);
                float4 x4 = *reinterpret_cast<const float4*>(&y1[c4]);
                s += w4.x * x4.x + w4.y * x4.y + w4.z * x4.z + w4.w * x4.w;
            }
            float y = fc2_g[t] * s * BN_INV + fc2_b[t];
            y2s[t] = (y >= 0.f) ? y : 0.2f * y;
        }
        __syncthreads();
        float v0 = y2s[0], v1 = y2s[1], v2 = y2s[2];
        v4f pat0 = {v0, v1, v2, v0};
        v4f pat1 = {v1, v2, v0, v1};
        v4f pat2 = {v2, v0, v1, v2};
        // f = t + i*256; since 256 % 3 == 1, f % 3 == (t + i) % 3.
        int r = t % 3;
        v4f a = (r == 0) ? pat0 : (r == 1) ? pat1 : pat2;
        v4f bb = (r == 0) ? pat1 : (r == 1) ? pat2 : pat0;
        v4f c = (r == 0) ? pat2 : (r == 1) ? pat0 : pat1;
        v4f* o1 = reinterpret_cast<v4f*>(
            out + (size_t)B_ * C_ * N_ + (size_t)b * (N_ * 3));
        #pragma unroll
        for (int i = 0; i < 24; i += 3) {    // 6144 float4 = 8192*3 f32
            __builtin_nontemporal_store(a,  &o1[t + (i + 0) * 256]);
            __builtin_nontemporal_store(bb, &o1[t + (i + 1) * 256]);
            __builtin_nontemporal_store(c,  &o1[t + (i + 2) * 256]);
        }
    }
}

// ---------------------------------------------------------------------------
extern "C" void kernel_launch(void* const* d_in, const int* in_sizes, int n_in,
                              void* d_out, int out_size, void* d_ws, size_t ws_size,
                              hipStream_t stream) {
    const float* xt      = (const float*)d_in[0];
    // d_in[1] = xn : unused (length N is compile-time)
    const float* weights = (const float*)d_in[2];
    const float* mt      = (const float*)d_in[3];
    const float* enc_w   = (const float*)d_in[4];
    const float* enc_b   = (const float*)d_in[5];
    const float* dec_w   = (const float*)d_in[6];
    const float* dec_b   = (const float*)d_in[7];
    const float* fc1_w   = (const float*)d_in[8];
    const float* fc1_g   = (const float*)d_in[9];
    const float* fc1_b   = (const float*)d_in[10];
    const float* fc2_w   = (const float*)d_in[11];
    const float* fc2_g   = (const float*)d_in[12];
    const float* fc2_b   = (const float*)d_in[13];

    float* ws  = (float*)d_ws;
    float* xnp = ws;                  // 4096 floats

    float* out = (float*)d_out;

    fused_enc<<<128, 1024, 0, stream>>>(xt, enc_w, enc_b, weights,
                                        dec_w, dec_b, mt, xnp);
    bcast_fc<<<4112, 256, 0, stream>>>(xnp, fc1_w, fc1_g, fc1_b,
                                       fc2_w, fc2_g, fc2_b, out);
}

// Round 20
// 57.916 us; speedup vs baseline: 1.1001x; 1.1001x over previous
//
#include <hip/hip_runtime.h>
#include <hip/hip_bf16.h>
#include <math.h>

// Problem constants
#define B_    16
#define C_    256
#define L_    64
#define N_    8192
#define HEAD_ 8
#define HC_   32        // C/HEAD
#define M_    12

#define SQRT32F 5.656854249492380f
#define PI_F    3.14159265358979323846f
#define BN_INV  0.99999500003749969f     // 1/sqrt(1+1e-5)

typedef float v4f __attribute__((ext_vector_type(4)));

// ---------------------------------------------------------------------------
// Kernel 1: fused encoder+decoder+out0 per (b,h). 128 blocks x 512 threads.
// Phases 1-4 are the R14 kernel VERBATIM (52.4 us best). Phase 5 (new):
// each block streams the 32 out0 rows for its own channels (1 MB, nt) --
// deleting the 4096-block broadcast kernel and its launch/scheduling ramp.
// ---------------------------------------------------------------------------
__global__ __launch_bounds__(512) void fused_enc(
    const float* __restrict__ xt, const float* __restrict__ enc_w,
    const float* __restrict__ enc_b, const float* __restrict__ weights,
    const float* __restrict__ dec_w, const float* __restrict__ dec_b,
    const float* __restrict__ mt, float* __restrict__ xnp_out,
    float* __restrict__ out)
{
    __shared__ float Xs[C_][L_];          // 64 KB   xt[b] as [c][l]
    __shared__ float qkv_s[96][68];       // 26.1 KB rows 0..31 q, 32..63 k, 64..95 v
    __shared__ float P[L_][68];           // 17.4 KB
    __shared__ float enc_t[HC_][68];      // 8.7 KB
    __shared__ float wts[HC_][24];        // 3 KB
    __shared__ float qvs[HC_];
    __shared__ float aw[L_];
    __shared__ float xnp_s[HC_];
    const int t = threadIdx.x;            // 0..511
    const int b = blockIdx.x >> 3;
    const int h = blockIdx.x & 7;
    const float* xtb = xt + (size_t)b * (C_ * L_);

    // ---- phase 1: stage xt[b] + weights slice ----
    #pragma unroll
    for (int i = 0; i < 8; ++i) {
        int q = t + i * 512;
        int c = q >> 4, l4 = (q & 15) * 4;
        *reinterpret_cast<float4*>(&Xs[c][l4]) =
            *reinterpret_cast<const float4*>(&xtb[q * 4]);
    }
    #pragma unroll
    for (int idx = t; idx < HC_ * 24; idx += 512)
        wts[idx / 24][idx % 24] = weights[(h * HC_) * 24 + idx];
    __syncthreads();

    // ---- phase 2: qkv GEMM (R12/R14 proven form, 3 rows x 4 cols / thread) ----
    {
        const int tx = t & 15, ty = t >> 4;    // ty 0..31: rows ty*3..+2
        float acc[3][4] = {};
        int og[3];
        const float* wrow[3];
        #pragma unroll
        for (int r = 0; r < 3; ++r) {
            int o_loc = ty * 3 + r;            // 0..95
            int sec = o_loc >> 5, cc = o_loc & 31;
            og[r] = sec * C_ + h * HC_ + cc;
            wrow[r] = enc_w + (size_t)og[r] * C_;
        }
        #pragma unroll 2
        for (int c0 = 0; c0 < C_; c0 += 4) {
            float4 x0 = *reinterpret_cast<const float4*>(&Xs[c0 + 0][tx * 4]);
            float4 x1 = *reinterpret_cast<const float4*>(&Xs[c0 + 1][tx * 4]);
            float4 x2 = *reinterpret_cast<const float4*>(&Xs[c0 + 2][tx * 4]);
            float4 x3 = *reinterpret_cast<const float4*>(&Xs[c0 + 3][tx * 4]);
            #pragma unroll
            for (int r = 0; r < 3; ++r) {
                float4 w4 = *reinterpret_cast<const float4*>(&wrow[r][c0]);
                acc[r][0] += w4.x * x0.x + w4.y * x1.x + w4.z * x2.x + w4.w * x3.x;
                acc[r][1] += w4.x * x0.y + w4.y * x1.y + w4.z * x2.y + w4.w * x3.y;
                acc[r][2] += w4.x * x0.z + w4.y * x1.z + w4.z * x2.z + w4.w * x3.z;
                acc[r][3] += w4.x * x0.w + w4.y * x1.w + w4.z * x2.w + w4.w * x3.w;
            }
        }
        #pragma unroll
        for (int r = 0; r < 3; ++r) {
            float bias = enc_b[og[r]];
            float4 v = make_float4(acc[r][0] + bias, acc[r][1] + bias,
                                   acc[r][2] + bias, acc[r][3] + bias);
            *reinterpret_cast<float4*>(&qkv_s[ty * 3 + r][tx * 4]) = v;
        }
    }
    // qv: 32 rows x 4 partial-threads, shfl-xor combine
    if (t < 128) {
        int cc = t >> 2, part = t & 3;
        const float* wr = dec_w + (size_t)(h * HC_ + cc) * C_ + part * 64;
        const float* mp = mt + part * 64;
        float s = 0.f;
        #pragma unroll
        for (int j = 0; j < 16; ++j) {
            float4 w4 = *reinterpret_cast<const float4*>(&wr[j * 4]);
            float4 m4 = *reinterpret_cast<const float4*>(&mp[j * 4]);
            s += w4.x * m4.x + w4.y * m4.y + w4.z * m4.z + w4.w * m4.w;
        }
        s += __shfl_xor(s, 1);
        s += __shfl_xor(s, 2);
        if (part == 0) qvs[cc] = s + dec_b[h * HC_ + cc];
    }
    __syncthreads();

    // ---- phase 3a: scores, 2l x 4lp tile, ALL 512 threads ----
    {
        const int l0  = (t >> 4) * 2;
        const int lp0 = (t & 15) * 4;
        float sc[2][4] = {};
        #pragma unroll
        for (int cc = 0; cc < HC_; ++cc) {
            float2 q2 = *reinterpret_cast<const float2*>(&qkv_s[cc][l0]);
            float4 k4 = *reinterpret_cast<const float4*>(&qkv_s[32 + cc][lp0]);
            sc[0][0] += q2.x * k4.x; sc[0][1] += q2.x * k4.y;
            sc[0][2] += q2.x * k4.z; sc[0][3] += q2.x * k4.w;
            sc[1][0] += q2.y * k4.x; sc[1][1] += q2.y * k4.y;
            sc[1][2] += q2.y * k4.z; sc[1][3] += q2.y * k4.w;
        }
        #pragma unroll
        for (int i = 0; i < 2; ++i) {
            float4 v = make_float4(sc[i][0] * SQRT32F, sc[i][1] * SQRT32F,
                                   sc[i][2] * SQRT32F, sc[i][3] * SQRT32F);
            *reinterpret_cast<float4*>(&P[l0 + i][lp0]) = v;
        }
    }
    __syncthreads();

    // ---- phase 3b: softmax, 8 threads/row, ALL 512 threads ----
    {
        int l = t >> 3, p0 = (t & 7) * 8;
        float m = -1e30f;
        #pragma unroll
        for (int j = 0; j < 8; ++j) m = fmaxf(m, P[l][p0 + j]);
        m = fmaxf(m, __shfl_xor(m, 1));
        m = fmaxf(m, __shfl_xor(m, 2));
        m = fmaxf(m, __shfl_xor(m, 4));
        float sum = 0.f;
        #pragma unroll
        for (int j = 0; j < 8; ++j) {
            float e = __expf(P[l][p0 + j] - m);
            P[l][p0 + j] = e;
            sum += e;
        }
        sum += __shfl_xor(sum, 1);
        sum += __shfl_xor(sum, 2);
        sum += __shfl_xor(sum, 4);
        float inv = 1.0f / sum;
        #pragma unroll
        for (int j = 0; j < 8; ++j) P[l][p0 + j] *= inv;
    }
    __syncthreads();

    // ---- phase 3c: PV (2l x 2cc) + Fourier recurrence + residual ----
    {
        const int l0 = (t & 31) * 2;
        const int c0 = (t >> 5) * 2;
        float a[2][2] = {};
        #pragma unroll
        for (int sq = 0; sq < 16; ++sq) {
            float4 p0v = *reinterpret_cast<const float4*>(&P[l0 + 0][sq * 4]);
            float4 p1v = *reinterpret_cast<const float4*>(&P[l0 + 1][sq * 4]);
            float4 v0v = *reinterpret_cast<const float4*>(&qkv_s[64 + c0 + 0][sq * 4]);
            float4 v1v = *reinterpret_cast<const float4*>(&qkv_s[64 + c0 + 1][sq * 4]);
            a[0][0] += p0v.x * v0v.x + p0v.y * v0v.y + p0v.z * v0v.z + p0v.w * v0v.w;
            a[0][1] += p0v.x * v1v.x + p0v.y * v1v.y + p0v.z * v1v.z + p0v.w * v1v.w;
            a[1][0] += p1v.x * v0v.x + p1v.y * v0v.y + p1v.z * v0v.z + p1v.w * v0v.w;
            a[1][1] += p1v.x * v1v.x + p1v.y * v1v.y + p1v.z * v1v.z + p1v.w * v1v.w;
        }
        #pragma unroll
        for (int j = 0; j < 2; ++j) {
            int cc = c0 + j;
            int c  = h * HC_ + cc;
            const float* wrf = wts[cc];
            float vv[2];
            #pragma unroll
            for (int i = 0; i < 2; ++i) {
                float val = Xs[c][l0 + i] + wrf[M_];   // m=0: sin=0, cos=1
                float base = a[i][j] * (PI_F / (float)M_);
                float s1, c1;
                __sincosf(base, &s1, &c1);
                float sm = 0.f, cm = 1.f;
                #pragma unroll
                for (int m = 1; m < M_; ++m) {
                    float sp = sm * c1 + cm * s1;
                    float cp = cm * c1 - sm * s1;
                    sm = sp; cm = cp;
                    val += wrf[m] * sm + wrf[M_ + m] * cm;
                }
                vv[i] = val;
            }
            *reinterpret_cast<float2*>(&enc_t[cc][l0]) =
                make_float2(vv[0], vv[1]);
        }
    }
    __syncthreads();

    // ---- phase 4: decoder attention (constant query) ----
    if (t < L_) {
        float s = 0.f;
        #pragma unroll
        for (int cc = 0; cc < HC_; ++cc) s += qvs[cc] * enc_t[cc][t];
        s *= SQRT32F;
        float m = s;
        #pragma unroll
        for (int off = 32; off >= 1; off >>= 1) m = fmaxf(m, __shfl_xor(m, off));
        float e = __expf(s - m);
        float sum = e;
        #pragma unroll
        for (int off = 32; off >= 1; off >>= 1) sum += __shfl_xor(sum, off);
        aw[t] = e / sum;
    }
    __syncthreads();
    if (t < HC_) {
        float a = 0.f;
        #pragma unroll
        for (int k4 = 0; k4 < L_; k4 += 4) {
            float4 a4 = *reinterpret_cast<const float4*>(&aw[k4]);
            float4 v4 = *reinterpret_cast<const float4*>(&enc_t[t][k4]);
            a += a4.x * v4.x + a4.y * v4.y + a4.z * v4.z + a4.w * v4.w;
        }
        int c = h * HC_ + t;
        float x = a + mt[c];
        xnp_s[t] = x;
        xnp_out[b * C_ + c] = x;
    }
    __syncthreads();

    // ---- phase 5 (new): stream out0 rows for this block's 32 channels ----
    {
        float* base = out + ((size_t)b * C_ + h * HC_) * N_;
        #pragma unroll 4
        for (int r = 0; r < HC_; ++r) {
            float v = xnp_s[r];
            v4f V = {v, v, v, v};
            v4f* rp = reinterpret_cast<v4f*>(base + (size_t)r * N_);
            #pragma unroll
            for (int i = 0; i < 4; ++i)
                __builtin_nontemporal_store(V, &rp[t + i * 512]);  // 2048 x 16B
        }
    }
}

// ---------------------------------------------------------------------------
// Kernel 2: fc1/fc2 + out1 only. 16 blocks x 256 threads (R14-proven path).
// ---------------------------------------------------------------------------
__global__ __launch_bounds__(256) void fc_out1(const float* __restrict__ xnp,
                                               const float* __restrict__ fc1_w,
                                               const float* __restrict__ fc1_g,
                                               const float* __restrict__ fc1_b,
                                               const float* __restrict__ fc2_w,
                                               const float* __restrict__ fc2_g,
                                               const float* __restrict__ fc2_b,
                                               float* __restrict__ out) {
    const int t = threadIdx.x;
    const int b = blockIdx.x;
    __shared__ float xs[C_];
    __shared__ float y1[C_];
    __shared__ float y2s[4];
    xs[t] = xnp[b * C_ + t];
    __syncthreads();
    // fc1 + BN + LeakyReLU
    {
        const float* wrow = fc1_w + (size_t)t * C_;
        float s = 0.f;
        #pragma unroll 8
        for (int c4 = 0; c4 < C_; c4 += 4) {
            float4 w4 = *reinterpret_cast<const float4*>(&wrow[c4]);
            float4 x4 = *reinterpret_cast<const float4*>(&xs[c4]);
            s += w4.x * x4.x + w4.y * x4.y + w4.z * x4.z + w4.w * x4.w;
        }
        float y = fc1_g[t] * s * BN_INV + fc1_b[t];
        y1[t] = (y >= 0.f) ? y : 0.2f * y;
    }
    __syncthreads();
    if (t < 3) {
        const float* wrow = fc2_w + t * C_;
        float s = 0.f;
        #pragma unroll 8
        for (int c4 = 0; c4 < C_; c4 += 4) {
            float4 w4 = *reinterpret_cast<const float4*>(&wrow[c4]);
            float4 x4 = *reinterpret_cast<const float4*>(&y1[c4]);
            s += w4.x * x4.x + w4.y * x4.y + w4.z * x4.z + w4.w * x4.w;
        }
        float y = fc2_g[t] * s * BN_INV + fc2_b[t];
        y2s[t] = (y >= 0.f) ? y : 0.2f * y;
    }
    __syncthreads();
    float v0 = y2s[0], v1 = y2s[1], v2 = y2s[2];
    v4f pat0 = {v0, v1, v2, v0};
    v4f pat1 = {v1, v2, v0, v1};
    v4f pat2 = {v2, v0, v1, v2};
    // f = t + i*256; since 256 % 3 == 1, f % 3 == (t + i) % 3.
    int r = t % 3;
    v4f a = (r == 0) ? pat0 : (r == 1) ? pat1 : pat2;
    v4f bb = (r == 0) ? pat1 : (r == 1) ? pat2 : pat0;
    v4f c = (r == 0) ? pat2 : (r == 1) ? pat0 : pat1;
    v4f* o1 = reinterpret_cast<v4f*>(
        out + (size_t)B_ * C_ * N_ + (size_t)b * (N_ * 3));
    #pragma unroll
    for (int i = 0; i < 24; i += 3) {    // 6144 float4 = 8192*3 f32
        __builtin_nontemporal_store(a,  &o1[t + (i + 0) * 256]);
        __builtin_nontemporal_store(bb, &o1[t + (i + 1) * 256]);
        __builtin_nontemporal_store(c,  &o1[t + (i + 2) * 256]);
    }
}

// ---------------------------------------------------------------------------
extern "C" void kernel_launch(void* const* d_in, const int* in_sizes, int n_in,
                              void* d_out, int out_size, void* d_ws, size_t ws_size,
                              hipStream_t stream) {
    const float* xt      = (const float*)d_in[0];
    // d_in[1] = xn : unused (length N is compile-time)
    const float* weights = (const float*)d_in[2];
    const float* mt      = (const float*)d_in[3];
    const float* enc_w   = (const float*)d_in[4];
    const float* enc_b   = (const float*)d_in[5];
    const float* dec_w   = (const float*)d_in[6];
    const float* dec_b   = (const float*)d_in[7];
    const float* fc1_w   = (const float*)d_in[8];
    const float* fc1_g   = (const float*)d_in[9];
    const float* fc1_b   = (const float*)d_in[10];
    const float* fc2_w   = (const float*)d_in[11];
    const float* fc2_g   = (const float*)d_in[12];
    const float* fc2_b   = (const float*)d_in[13];

    float* ws  = (float*)d_ws;
    float* xnp = ws;                  // 4096 floats

    float* out = (float*)d_out;

    fused_enc<<<128, 512, 0, stream>>>(xt, enc_w, enc_b, weights,
                                       dec_w, dec_b, mt, xnp, out);
    fc_out1<<<16, 256, 0, stream>>>(xnp, fc1_w, fc1_g, fc1_b,
                                    fc2_w, fc2_g, fc2_b, out);
}

// Round 21
// 52.413 us; speedup vs baseline: 1.2156x; 1.1050x over previous
//
#include <hip/hip_runtime.h>
#include <hip/hip_bf16.h>
#include <math.h>

// Problem constants
#define B_    16
#define C_    256
#define L_    64
#define N_    8192
#define HEAD_ 8
#define HC_   32        // C/HEAD
#define M_    12

#define SQRT32F 5.656854249492380f
#define PI_F    3.14159265358979323846f
#define BN_INV  0.99999500003749969f     // 1/sqrt(1+1e-5)

typedef float v4f __attribute__((ext_vector_type(4)));

// ---------------------------------------------------------------------------
// Kernel 1: fused encoder+decoder per (b,h). 128 blocks x 512 threads.
// R14 VERBATIM -- the empirical optimum (52.4 us). GEMM: full-K, 3 rows x
// 4 cols/thread; scores/softmax/PV on all 512 threads; Fourier recurrence.
// ---------------------------------------------------------------------------
__global__ __launch_bounds__(512) void fused_enc(
    const float* __restrict__ xt, const float* __restrict__ enc_w,
    const float* __restrict__ enc_b, const float* __restrict__ weights,
    const float* __restrict__ dec_w, const float* __restrict__ dec_b,
    const float* __restrict__ mt, float* __restrict__ xnp_out)
{
    __shared__ float Xs[C_][L_];          // 64 KB   xt[b] as [c][l]
    __shared__ float qkv_s[96][68];       // 26.1 KB rows 0..31 q, 32..63 k, 64..95 v
    __shared__ float P[L_][68];           // 17.4 KB
    __shared__ float enc_t[HC_][68];      // 8.7 KB
    __shared__ float wts[HC_][24];        // 3 KB    weights h-slice
    __shared__ float qvs[HC_];
    __shared__ float aw[L_];
    const int t = threadIdx.x;            // 0..511
    const int b = blockIdx.x >> 3;
    const int h = blockIdx.x & 7;
    const float* xtb = xt + (size_t)b * (C_ * L_);

    // ---- phase 1: stage xt[b] + weights slice ----
    #pragma unroll
    for (int i = 0; i < 8; ++i) {
        int q = t + i * 512;
        int c = q >> 4, l4 = (q & 15) * 4;
        *reinterpret_cast<float4*>(&Xs[c][l4]) =
            *reinterpret_cast<const float4*>(&xtb[q * 4]);
    }
    #pragma unroll
    for (int idx = t; idx < HC_ * 24; idx += 512)
        wts[idx / 24][idx % 24] = weights[(h * HC_) * 24 + idx];
    __syncthreads();

    // ---- phase 2: qkv GEMM (R12 proven form, 3 rows x 4 cols / thread) ----
    {
        const int tx = t & 15, ty = t >> 4;    // ty 0..31: rows ty*3..+2
        float acc[3][4] = {};
        int og[3];
        const float* wrow[3];
        #pragma unroll
        for (int r = 0; r < 3; ++r) {
            int o_loc = ty * 3 + r;            // 0..95
            int sec = o_loc >> 5, cc = o_loc & 31;
            og[r] = sec * C_ + h * HC_ + cc;
            wrow[r] = enc_w + (size_t)og[r] * C_;
        }
        #pragma unroll 2
        for (int c0 = 0; c0 < C_; c0 += 4) {
            float4 x0 = *reinterpret_cast<const float4*>(&Xs[c0 + 0][tx * 4]);
            float4 x1 = *reinterpret_cast<const float4*>(&Xs[c0 + 1][tx * 4]);
            float4 x2 = *reinterpret_cast<const float4*>(&Xs[c0 + 2][tx * 4]);
            float4 x3 = *reinterpret_cast<const float4*>(&Xs[c0 + 3][tx * 4]);
            #pragma unroll
            for (int r = 0; r < 3; ++r) {
                float4 w4 = *reinterpret_cast<const float4*>(&wrow[r][c0]);
                acc[r][0] += w4.x * x0.x + w4.y * x1.x + w4.z * x2.x + w4.w * x3.x;
                acc[r][1] += w4.x * x0.y + w4.y * x1.y + w4.z * x2.y + w4.w * x3.y;
                acc[r][2] += w4.x * x0.z + w4.y * x1.z + w4.z * x2.z + w4.w * x3.z;
                acc[r][3] += w4.x * x0.w + w4.y * x1.w + w4.z * x2.w + w4.w * x3.w;
            }
        }
        #pragma unroll
        for (int r = 0; r < 3; ++r) {
            float bias = enc_b[og[r]];
            float4 v = make_float4(acc[r][0] + bias, acc[r][1] + bias,
                                   acc[r][2] + bias, acc[r][3] + bias);
            *reinterpret_cast<float4*>(&qkv_s[ty * 3 + r][tx * 4]) = v;
        }
    }
    // qv: 32 rows x 4 partial-threads, shfl-xor combine
    if (t < 128) {
        int cc = t >> 2, part = t & 3;
        const float* wr = dec_w + (size_t)(h * HC_ + cc) * C_ + part * 64;
        const float* mp = mt + part * 64;
        float s = 0.f;
        #pragma unroll
        for (int j = 0; j < 16; ++j) {
            float4 w4 = *reinterpret_cast<const float4*>(&wr[j * 4]);
            float4 m4 = *reinterpret_cast<const float4*>(&mp[j * 4]);
            s += w4.x * m4.x + w4.y * m4.y + w4.z * m4.z + w4.w * m4.w;
        }
        s += __shfl_xor(s, 1);
        s += __shfl_xor(s, 2);
        if (part == 0) qvs[cc] = s + dec_b[h * HC_ + cc];
    }
    __syncthreads();

    // ---- phase 3a: scores, 2l x 4lp tile, ALL 512 threads ----
    {
        const int l0  = (t >> 4) * 2;     // 32 l-pairs
        const int lp0 = (t & 15) * 4;     // 16 key quads
        float sc[2][4] = {};
        #pragma unroll
        for (int cc = 0; cc < HC_; ++cc) {
            float2 q2 = *reinterpret_cast<const float2*>(&qkv_s[cc][l0]);
            float4 k4 = *reinterpret_cast<const float4*>(&qkv_s[32 + cc][lp0]);
            sc[0][0] += q2.x * k4.x; sc[0][1] += q2.x * k4.y;
            sc[0][2] += q2.x * k4.z; sc[0][3] += q2.x * k4.w;
            sc[1][0] += q2.y * k4.x; sc[1][1] += q2.y * k4.y;
            sc[1][2] += q2.y * k4.z; sc[1][3] += q2.y * k4.w;
        }
        #pragma unroll
        for (int i = 0; i < 2; ++i) {
            float4 v = make_float4(sc[i][0] * SQRT32F, sc[i][1] * SQRT32F,
                                   sc[i][2] * SQRT32F, sc[i][3] * SQRT32F);
            *reinterpret_cast<float4*>(&P[l0 + i][lp0]) = v;
        }
    }
    __syncthreads();

    // ---- phase 3b: softmax, 8 threads/row, ALL 512 threads ----
    {
        int l = t >> 3, p0 = (t & 7) * 8;
        float m = -1e30f;
        #pragma unroll
        for (int j = 0; j < 8; ++j) m = fmaxf(m, P[l][p0 + j]);
        m = fmaxf(m, __shfl_xor(m, 1));
        m = fmaxf(m, __shfl_xor(m, 2));
        m = fmaxf(m, __shfl_xor(m, 4));
        float sum = 0.f;
        #pragma unroll
        for (int j = 0; j < 8; ++j) {
            float e = __expf(P[l][p0 + j] - m);
            P[l][p0 + j] = e;
            sum += e;
        }
        sum += __shfl_xor(sum, 1);
        sum += __shfl_xor(sum, 2);
        sum += __shfl_xor(sum, 4);
        float inv = 1.0f / sum;
        #pragma unroll
        for (int j = 0; j < 8; ++j) P[l][p0 + j] *= inv;
    }
    __syncthreads();

    // ---- phase 3c: PV (2l x 2cc) + Fourier recurrence + residual, 512 thr ----
    {
        const int l0 = (t & 31) * 2;      // 32 l-pairs
        const int c0 = (t >> 5) * 2;      // 16 cc-pairs
        float a[2][2] = {};
        #pragma unroll
        for (int sq = 0; sq < 16; ++sq) {
            float4 p0v = *reinterpret_cast<const float4*>(&P[l0 + 0][sq * 4]);
            float4 p1v = *reinterpret_cast<const float4*>(&P[l0 + 1][sq * 4]);
            float4 v0v = *reinterpret_cast<const float4*>(&qkv_s[64 + c0 + 0][sq * 4]);
            float4 v1v = *reinterpret_cast<const float4*>(&qkv_s[64 + c0 + 1][sq * 4]);
            a[0][0] += p0v.x * v0v.x + p0v.y * v0v.y + p0v.z * v0v.z + p0v.w * v0v.w;
            a[0][1] += p0v.x * v1v.x + p0v.y * v1v.y + p0v.z * v1v.z + p0v.w * v1v.w;
            a[1][0] += p1v.x * v0v.x + p1v.y * v0v.y + p1v.z * v0v.z + p1v.w * v0v.w;
            a[1][1] += p1v.x * v1v.x + p1v.y * v1v.y + p1v.z * v1v.z + p1v.w * v1v.w;
        }
        #pragma unroll
        for (int j = 0; j < 2; ++j) {
            int cc = c0 + j;
            int c  = h * HC_ + cc;
            const float* wrf = wts[cc];
            float vv[2];
            #pragma unroll
            for (int i = 0; i < 2; ++i) {
                float val = Xs[c][l0 + i] + wrf[M_];   // m=0: sin=0, cos=1
                float base = a[i][j] * (PI_F / (float)M_);
                float s1, c1;
                __sincosf(base, &s1, &c1);
                float sm = 0.f, cm = 1.f;
                #pragma unroll
                for (int m = 1; m < M_; ++m) {
                    float sp = sm * c1 + cm * s1;
                    float cp = cm * c1 - sm * s1;
                    sm = sp; cm = cp;
                    val += wrf[m] * sm + wrf[M_ + m] * cm;
                }
                vv[i] = val;
            }
            *reinterpret_cast<float2*>(&enc_t[cc][l0]) =
                make_float2(vv[0], vv[1]);
        }
    }
    __syncthreads();

    // ---- phase 4: decoder attention (constant query) ----
    if (t < L_) {
        float s = 0.f;
        #pragma unroll
        for (int cc = 0; cc < HC_; ++cc) s += qvs[cc] * enc_t[cc][t];
        s *= SQRT32F;
        float m = s;
        #pragma unroll
        for (int off = 32; off >= 1; off >>= 1) m = fmaxf(m, __shfl_xor(m, off));
        float e = __expf(s - m);
        float sum = e;
        #pragma unroll
        for (int off = 32; off >= 1; off >>= 1) sum += __shfl_xor(sum, off);
        aw[t] = e / sum;
    }
    __syncthreads();
    if (t < HC_) {
        float a = 0.f;
        #pragma unroll
        for (int k4 = 0; k4 < L_; k4 += 4) {
            float4 a4 = *reinterpret_cast<const float4*>(&aw[k4]);
            float4 v4 = *reinterpret_cast<const float4*>(&enc_t[t][k4]);
            a += a4.x * v4.x + a4.y * v4.y + a4.z * v4.z + a4.w * v4.w;
        }
        int c = h * HC_ + t;
        xnp_out[b * C_ + c] = a + mt[c];
    }
}

// ---------------------------------------------------------------------------
// Kernel 2: fc blocks first, nontemporal streaming stores. (proven R10)
// ---------------------------------------------------------------------------
__global__ __launch_bounds__(256) void bcast_fc(const float* __restrict__ xnp,
                                                const float* __restrict__ fc1_w,
                                                const float* __restrict__ fc1_g,
                                                const float* __restrict__ fc1_b,
                                                const float* __restrict__ fc2_w,
                                                const float* __restrict__ fc2_g,
                                                const float* __restrict__ fc2_b,
                                                float* __restrict__ out) {
    const int t = threadIdx.x;
    const int blk = blockIdx.x;
    if (blk >= 16) {
        int rowid = blk - 16;                 // (b,c) row
        float v = xnp[rowid];
        v4f V = {v, v, v, v};
        v4f* row = reinterpret_cast<v4f*>(out + (size_t)rowid * N_);
        #pragma unroll
        for (int i = 0; i < 8; ++i)
            __builtin_nontemporal_store(V, &row[t + i * 256]);   // 2048 x 16B
    } else {
        int b = blk;
        __shared__ float xs[C_];
        __shared__ float y1[C_];
        __shared__ float y2s[4];
        xs[t] = xnp[b * C_ + t];
        __syncthreads();
        // fc1 + BN + LeakyReLU
        {
            const float* wrow = fc1_w + (size_t)t * C_;
            float s = 0.f;
            #pragma unroll 8
            for (int c4 = 0; c4 < C_; c4 += 4) {
                float4 w4 = *reinterpret_cast<const float4*>(&wrow[c4]);
                float4 x4 = *reinterpret_cast<const float4*>(&xs[c4]);
                s += w4.x * x4.x + w4.y * x4.y + w4.z * x4.z + w4.w * x4.w;
            }
            float y = fc1_g[t] * s * BN_INV + fc1_b[t];
            y1[t] = (y >= 0.f) ? y : 0.2f * y;
        }
        __syncthreads();
        if (t < 3) {
            const float* wrow = fc2_w + t * C_;
            float s = 0.f;
            #pragma unroll 8
            for (int c4 = 0; c4 < C_; c4 += 4) {
                float4 w4 = *reinterpret_cast<const float4*>(&wrow[c4]);
                float4 x4 = *reinterpret_cast<const float4*>(&y1[c4]);
                s += w4.x * x4.x + w4.y * x4.y + w4.z * x4.z + w4.w * x4.w;
            }
            float y = fc2_g[t] * s * BN_INV + fc2_b[t];
            y2s[t] = (y >= 0.f) ? y : 0.2f * y;
        }
        __syncthreads();
        float v0 = y2s[0], v1 = y2s[1], v2 = y2s[2];
        v4f pat0 = {v0, v1, v2, v0};
        v4f pat1 = {v1, v2, v0, v1};
        v4f pat2 = {v2, v0, v1, v2};
        // f = t + i*256; since 256 % 3 == 1, f % 3 == (t + i) % 3.
        int r = t % 3;
        v4f a = (r == 0) ? pat0 : (r == 1) ? pat1 : pat2;
        v4f bb = (r == 0) ? pat1 : (r == 1) ? pat2 : pat0;
        v4f c = (r == 0) ? pat2 : (r == 1) ? pat0 : pat1;
        v4f* o1 = reinterpret_cast<v4f*>(
            out + (size_t)B_ * C_ * N_ + (size_t)b * (N_ * 3));
        #pragma unroll
        for (int i = 0; i < 24; i += 3) {    // 6144 float4 = 8192*3 f32
            __builtin_nontemporal_store(a,  &o1[t + (i + 0) * 256]);
            __builtin_nontemporal_store(bb, &o1[t + (i + 1) * 256]);
            __builtin_nontemporal_store(c,  &o1[t + (i + 2) * 256]);
        }
    }
}

// ---------------------------------------------------------------------------
extern "C" void kernel_launch(void* const* d_in, const int* in_sizes, int n_in,
                              void* d_out, int out_size, void* d_ws, size_t ws_size,
                              hipStream_t stream) {
    const float* xt      = (const float*)d_in[0];
    // d_in[1] = xn : unused (length N is compile-time)
    const float* weights = (const float*)d_in[2];
    const float* mt      = (const float*)d_in[3];
    const float* enc_w   = (const float*)d_in[4];
    const float* enc_b   = (const float*)d_in[5];
    const float* dec_w   = (const float*)d_in[6];
    const float* dec_b   = (const float*)d_in[7];
    const float* fc1_w   = (const float*)d_in[8];
    const float* fc1_g   = (const float*)d_in[9];
    const float* fc1_b   = (const float*)d_in[10];
    const float* fc2_w   = (const float*)d_in[11];
    const float* fc2_g   = (const float*)d_in[12];
    const float* fc2_b   = (const float*)d_in[13];

    float* ws  = (float*)d_ws;
    float* xnp = ws;                  // 4096 floats

    float* out = (float*)d_out;

    fused_enc<<<128, 512, 0, stream>>>(xt, enc_w, enc_b, weights,
                                       dec_w, dec_b, mt, xnp);
    bcast_fc<<<4112, 256, 0, stream>>>(xnp, fc1_w, fc1_g, fc1_b,
                                       fc2_w, fc2_g, fc2_b, out);
}

// Round 22
// 52.355 us; speedup vs baseline: 1.2170x; 1.0011x over previous
//
#include <hip/hip_runtime.h>
#include <hip/hip_bf16.h>
#include <math.h>

// Problem constants
#define B_    16
#define C_    256
#define L_    64
#define N_    8192
#define HEAD_ 8
#define HC_   32        // C/HEAD
#define M_    12

#define SQRT32F 5.656854249492380f
#define PI_F    3.14159265358979323846f
#define BN_INV  0.99999500003749969f     // 1/sqrt(1+1e-5)

typedef float v4f __attribute__((ext_vector_type(4)));

// ---------------------------------------------------------------------------
// Kernel 1: fused encoder+decoder per (b,h). 128 blocks x 512 threads.
// R14 VERBATIM -- the empirical optimum (52.4 us). GEMM: full-K, 3 rows x
// 4 cols/thread; scores/softmax/PV on all 512 threads; Fourier recurrence.
// ---------------------------------------------------------------------------
__global__ __launch_bounds__(512) void fused_enc(
    const float* __restrict__ xt, const float* __restrict__ enc_w,
    const float* __restrict__ enc_b, const float* __restrict__ weights,
    const float* __restrict__ dec_w, const float* __restrict__ dec_b,
    const float* __restrict__ mt, float* __restrict__ xnp_out)
{
    __shared__ float Xs[C_][L_];          // 64 KB   xt[b] as [c][l]
    __shared__ float qkv_s[96][68];       // 26.1 KB rows 0..31 q, 32..63 k, 64..95 v
    __shared__ float P[L_][68];           // 17.4 KB
    __shared__ float enc_t[HC_][68];      // 8.7 KB
    __shared__ float wts[HC_][24];        // 3 KB    weights h-slice
    __shared__ float qvs[HC_];
    __shared__ float aw[L_];
    const int t = threadIdx.x;            // 0..511
    const int b = blockIdx.x >> 3;
    const int h = blockIdx.x & 7;
    const float* xtb = xt + (size_t)b * (C_ * L_);

    // ---- phase 1: stage xt[b] + weights slice ----
    #pragma unroll
    for (int i = 0; i < 8; ++i) {
        int q = t + i * 512;
        int c = q >> 4, l4 = (q & 15) * 4;
        *reinterpret_cast<float4*>(&Xs[c][l4]) =
            *reinterpret_cast<const float4*>(&xtb[q * 4]);
    }
    #pragma unroll
    for (int idx = t; idx < HC_ * 24; idx += 512)
        wts[idx / 24][idx % 24] = weights[(h * HC_) * 24 + idx];
    __syncthreads();

    // ---- phase 2: qkv GEMM (R12 proven form, 3 rows x 4 cols / thread) ----
    {
        const int tx = t & 15, ty = t >> 4;    // ty 0..31: rows ty*3..+2
        float acc[3][4] = {};
        int og[3];
        const float* wrow[3];
        #pragma unroll
        for (int r = 0; r < 3; ++r) {
            int o_loc = ty * 3 + r;            // 0..95
            int sec = o_loc >> 5, cc = o_loc & 31;
            og[r] = sec * C_ + h * HC_ + cc;
            wrow[r] = enc_w + (size_t)og[r] * C_;
        }
        #pragma unroll 2
        for (int c0 = 0; c0 < C_; c0 += 4) {
            float4 x0 = *reinterpret_cast<const float4*>(&Xs[c0 + 0][tx * 4]);
            float4 x1 = *reinterpret_cast<const float4*>(&Xs[c0 + 1][tx * 4]);
            float4 x2 = *reinterpret_cast<const float4*>(&Xs[c0 + 2][tx * 4]);
            float4 x3 = *reinterpret_cast<const float4*>(&Xs[c0 + 3][tx * 4]);
            #pragma unroll
            for (int r = 0; r < 3; ++r) {
                float4 w4 = *reinterpret_cast<const float4*>(&wrow[r][c0]);
                acc[r][0] += w4.x * x0.x + w4.y * x1.x + w4.z * x2.x + w4.w * x3.x;
                acc[r][1] += w4.x * x0.y + w4.y * x1.y + w4.z * x2.y + w4.w * x3.y;
                acc[r][2] += w4.x * x0.z + w4.y * x1.z + w4.z * x2.z + w4.w * x3.z;
                acc[r][3] += w4.x * x0.w + w4.y * x1.w + w4.z * x2.w + w4.w * x3.w;
            }
        }
        #pragma unroll
        for (int r = 0; r < 3; ++r) {
            float bias = enc_b[og[r]];
            float4 v = make_float4(acc[r][0] + bias, acc[r][1] + bias,
                                   acc[r][2] + bias, acc[r][3] + bias);
            *reinterpret_cast<float4*>(&qkv_s[ty * 3 + r][tx * 4]) = v;
        }
    }
    // qv: 32 rows x 4 partial-threads, shfl-xor combine
    if (t < 128) {
        int cc = t >> 2, part = t & 3;
        const float* wr = dec_w + (size_t)(h * HC_ + cc) * C_ + part * 64;
        const float* mp = mt + part * 64;
        float s = 0.f;
        #pragma unroll
        for (int j = 0; j < 16; ++j) {
            float4 w4 = *reinterpret_cast<const float4*>(&wr[j * 4]);
            float4 m4 = *reinterpret_cast<const float4*>(&mp[j * 4]);
            s += w4.x * m4.x + w4.y * m4.y + w4.z * m4.z + w4.w * m4.w;
        }
        s += __shfl_xor(s, 1);
        s += __shfl_xor(s, 2);
        if (part == 0) qvs[cc] = s + dec_b[h * HC_ + cc];
    }
    __syncthreads();

    // ---- phase 3a: scores, 2l x 4lp tile, ALL 512 threads ----
    {
        const int l0  = (t >> 4) * 2;     // 32 l-pairs
        const int lp0 = (t & 15) * 4;     // 16 key quads
        float sc[2][4] = {};
        #pragma unroll
        for (int cc = 0; cc < HC_; ++cc) {
            float2 q2 = *reinterpret_cast<const float2*>(&qkv_s[cc][l0]);
            float4 k4 = *reinterpret_cast<const float4*>(&qkv_s[32 + cc][lp0]);
            sc[0][0] += q2.x * k4.x; sc[0][1] += q2.x * k4.y;
            sc[0][2] += q2.x * k4.z; sc[0][3] += q2.x * k4.w;
            sc[1][0] += q2.y * k4.x; sc[1][1] += q2.y * k4.y;
            sc[1][2] += q2.y * k4.z; sc[1][3] += q2.y * k4.w;
        }
        #pragma unroll
        for (int i = 0; i < 2; ++i) {
            float4 v = make_float4(sc[i][0] * SQRT32F, sc[i][1] * SQRT32F,
                                   sc[i][2] * SQRT32F, sc[i][3] * SQRT32F);
            *reinterpret_cast<float4*>(&P[l0 + i][lp0]) = v;
        }
    }
    __syncthreads();

    // ---- phase 3b: softmax, 8 threads/row, ALL 512 threads ----
    {
        int l = t >> 3, p0 = (t & 7) * 8;
        float m = -1e30f;
        #pragma unroll
        for (int j = 0; j < 8; ++j) m = fmaxf(m, P[l][p0 + j]);
        m = fmaxf(m, __shfl_xor(m, 1));
        m = fmaxf(m, __shfl_xor(m, 2));
        m = fmaxf(m, __shfl_xor(m, 4));
        float sum = 0.f;
        #pragma unroll
        for (int j = 0; j < 8; ++j) {
            float e = __expf(P[l][p0 + j] - m);
            P[l][p0 + j] = e;
            sum += e;
        }
        sum += __shfl_xor(sum, 1);
        sum += __shfl_xor(sum, 2);
        sum += __shfl_xor(sum, 4);
        float inv = 1.0f / sum;
        #pragma unroll
        for (int j = 0; j < 8; ++j) P[l][p0 + j] *= inv;
    }
    __syncthreads();

    // ---- phase 3c: PV (2l x 2cc) + Fourier recurrence + residual, 512 thr ----
    {
        const int l0 = (t & 31) * 2;      // 32 l-pairs
        const int c0 = (t >> 5) * 2;      // 16 cc-pairs
        float a[2][2] = {};
        #pragma unroll
        for (int sq = 0; sq < 16; ++sq) {
            float4 p0v = *reinterpret_cast<const float4*>(&P[l0 + 0][sq * 4]);
            float4 p1v = *reinterpret_cast<const float4*>(&P[l0 + 1][sq * 4]);
            float4 v0v = *reinterpret_cast<const float4*>(&qkv_s[64 + c0 + 0][sq * 4]);
            float4 v1v = *reinterpret_cast<const float4*>(&qkv_s[64 + c0 + 1][sq * 4]);
            a[0][0] += p0v.x * v0v.x + p0v.y * v0v.y + p0v.z * v0v.z + p0v.w * v0v.w;
            a[0][1] += p0v.x * v1v.x + p0v.y * v1v.y + p0v.z * v1v.z + p0v.w * v1v.w;
            a[1][0] += p1v.x * v0v.x + p1v.y * v0v.y + p1v.z * v0v.z + p1v.w * v0v.w;
            a[1][1] += p1v.x * v1v.x + p1v.y * v1v.y + p1v.z * v1v.z + p1v.w * v1v.w;
        }
        #pragma unroll
        for (int j = 0; j < 2; ++j) {
            int cc = c0 + j;
            int c  = h * HC_ + cc;
            const float* wrf = wts[cc];
            float vv[2];
            #pragma unroll
            for (int i = 0; i < 2; ++i) {
                float val = Xs[c][l0 + i] + wrf[M_];   // m=0: sin=0, cos=1
                float base = a[i][j] * (PI_F / (float)M_);
                float s1, c1;
                __sincosf(base, &s1, &c1);
                float sm = 0.f, cm = 1.f;
                #pragma unroll
                for (int m = 1; m < M_; ++m) {
                    float sp = sm * c1 + cm * s1;
                    float cp = cm * c1 - sm * s1;
                    sm = sp; cm = cp;
                    val += wrf[m] * sm + wrf[M_ + m] * cm;
                }
                vv[i] = val;
            }
            *reinterpret_cast<float2*>(&enc_t[cc][l0]) =
                make_float2(vv[0], vv[1]);
        }
    }
    __syncthreads();

    // ---- phase 4: decoder attention (constant query) ----
    if (t < L_) {
        float s = 0.f;
        #pragma unroll
        for (int cc = 0; cc < HC_; ++cc) s += qvs[cc] * enc_t[cc][t];
        s *= SQRT32F;
        float m = s;
        #pragma unroll
        for (int off = 32; off >= 1; off >>= 1) m = fmaxf(m, __shfl_xor(m, off));
        float e = __expf(s - m);
        float sum = e;
        #pragma unroll
        for (int off = 32; off >= 1; off >>= 1) sum += __shfl_xor(sum, off);
        aw[t] = e / sum;
    }
    __syncthreads();
    if (t < HC_) {
        float a = 0.f;
        #pragma unroll
        for (int k4 = 0; k4 < L_; k4 += 4) {
            float4 a4 = *reinterpret_cast<const float4*>(&aw[k4]);
            float4 v4 = *reinterpret_cast<const float4*>(&enc_t[t][k4]);
            a += a4.x * v4.x + a4.y * v4.y + a4.z * v4.z + a4.w * v4.w;
        }
        int c = h * HC_ + t;
        xnp_out[b * C_ + c] = a + mt[c];
    }
}

// ---------------------------------------------------------------------------
// Kernel 2: fc blocks first, nontemporal streaming stores. (proven R10)
// ---------------------------------------------------------------------------
__global__ __launch_bounds__(256) void bcast_fc(const float* __restrict__ xnp,
                                                const float* __restrict__ fc1_w,
                                                const float* __restrict__ fc1_g,
                                                const float* __restrict__ fc1_b,
                                                const float* __restrict__ fc2_w,
                                                const float* __restrict__ fc2_g,
                                                const float* __restrict__ fc2_b,
                                                float* __restrict__ out) {
    const int t = threadIdx.x;
    const int blk = blockIdx.x;
    if (blk >= 16) {
        int rowid = blk - 16;                 // (b,c) row
        float v = xnp[rowid];
        v4f V = {v, v, v, v};
        v4f* row = reinterpret_cast<v4f*>(out + (size_t)rowid * N_);
        #pragma unroll
        for (int i = 0; i < 8; ++i)
            __builtin_nontemporal_store(V, &row[t + i * 256]);   // 2048 x 16B
    } else {
        int b = blk;
        __shared__ float xs[C_];
        __shared__ float y1[C_];
        __shared__ float y2s[4];
        xs[t] = xnp[b * C_ + t];
        __syncthreads();
        // fc1 + BN + LeakyReLU
        {
            const float* wrow = fc1_w + (size_t)t * C_;
            float s = 0.f;
            #pragma unroll 8
            for (int c4 = 0; c4 < C_; c4 += 4) {
                float4 w4 = *reinterpret_cast<const float4*>(&wrow[c4]);
                float4 x4 = *reinterpret_cast<const float4*>(&xs[c4]);
                s += w4.x * x4.x + w4.y * x4.y + w4.z * x4.z + w4.w * x4.w;
            }
            float y = fc1_g[t] * s * BN_INV + fc1_b[t];
            y1[t] = (y >= 0.f) ? y : 0.2f * y;
        }
        __syncthreads();
        if (t < 3) {
            const float* wrow = fc2_w + t * C_;
            float s = 0.f;
            #pragma unroll 8
            for (int c4 = 0; c4 < C_; c4 += 4) {
                float4 w4 = *reinterpret_cast<const float4*>(&wrow[c4]);
                float4 x4 = *reinterpret_cast<const float4*>(&y1[c4]);
                s += w4.x * x4.x + w4.y * x4.y + w4.z * x4.z + w4.w * x4.w;
            }
            float y = fc2_g[t] * s * BN_INV + fc2_b[t];
            y2s[t] = (y >= 0.f) ? y : 0.2f * y;
        }
        __syncthreads();
        float v0 = y2s[0], v1 = y2s[1], v2 = y2s[2];
        v4f pat0 = {v0, v1, v2, v0};
        v4f pat1 = {v1, v2, v0, v1};
        v4f pat2 = {v2, v0, v1, v2};
        // f = t + i*256; since 256 % 3 == 1, f % 3 == (t + i) % 3.
        int r = t % 3;
        v4f a = (r == 0) ? pat0 : (r == 1) ? pat1 : pat2;
        v4f bb = (r == 0) ? pat1 : (r == 1) ? pat2 : pat0;
        v4f c = (r == 0) ? pat2 : (r == 1) ? pat0 : pat1;
        v4f* o1 = reinterpret_cast<v4f*>(
            out + (size_t)B_ * C_ * N_ + (size_t)b * (N_ * 3));
        #pragma unroll
        for (int i = 0; i < 24; i += 3) {    // 6144 float4 = 8192*3 f32
            __builtin_nontemporal_store(a,  &o1[t + (i + 0) * 256]);
            __builtin_nontemporal_store(bb, &o1[t + (i + 1) * 256]);
            __builtin_nontemporal_store(c,  &o1[t + (i + 2) * 256]);
        }
    }
}

// ---------------------------------------------------------------------------
extern "C" void kernel_launch(void* const* d_in, const int* in_sizes, int n_in,
                              void* d_out, int out_size, void* d_ws, size_t ws_size,
                              hipStream_t stream) {
    const float* xt      = (const float*)d_in[0];
    // d_in[1] = xn : unused (length N is compile-time)
    const float* weights = (const float*)d_in[2];
    const float* mt      = (const float*)d_in[3];
    const float* enc_w   = (const float*)d_in[4];
    const float* enc_b   = (const float*)d_in[5];
    const float* dec_w   = (const float*)d_in[6];
    const float* dec_b   = (const float*)d_in[7];
    const float* fc1_w   = (const float*)d_in[8];
    const float* fc1_g   = (const float*)d_in[9];
    const float* fc1_b   = (const float*)d_in[10];
    const float* fc2_w   = (const float*)d_in[11];
    const float* fc2_g   = (const float*)d_in[12];
    const float* fc2_b   = (const float*)d_in[13];

    float* ws  = (float*)d_ws;
    float* xnp = ws;                  // 4096 floats

    float* out = (float*)d_out;

    fused_enc<<<128, 512, 0, stream>>>(xt, enc_w, enc_b, weights,
                                       dec_w, dec_b, mt, xnp);
    bcast_fc<<<4112, 256, 0, stream>>>(xnp, fc1_w, fc1_g, fc1_b,
                                       fc2_w, fc2_g, fc2_b, out);
}